// Round 11
// baseline (70.035 us; speedup 1.0000x reference)
//
#include <hip/hip_runtime.h>

typedef unsigned short ushort_t;
typedef __attribute__((ext_vector_type(4))) short short4_t;
typedef __attribute__((ext_vector_type(8))) short short8;
typedef __attribute__((ext_vector_type(4))) float floatx4;
typedef __attribute__((ext_vector_type(8))) __bf16 bf16x8;

__device__ __forceinline__ ushort_t f2b(float f) {
  union { float f; unsigned int i; } t; t.f = f;
  unsigned int u = t.i;
  return (ushort_t)((u + 0x7fffu + ((u >> 16) & 1u)) >> 16);  // RNE
}
__device__ __forceinline__ ushort_t cvtb(float f) {
  __bf16 h = (__bf16)f;                       // v_cvt RNE
  return __builtin_bit_cast(unsigned short, h);
}

__device__ __forceinline__ floatx4 mfma16(short8 a, short8 b, floatx4 c) {
  return __builtin_amdgcn_mfma_f32_16x16x32_bf16(
      __builtin_bit_cast(bf16x8, a), __builtin_bit_cast(bf16x8, b), c, 0, 0, 0);
}

__device__ __forceinline__ void gload16(const void* g, void* l) {
  __builtin_amdgcn_global_load_lds(
      (const __attribute__((address_space(1))) void*)g,
      (__attribute__((address_space(3))) void*)l, 16, 0, 0);
}

// ---------------------------------------------------------------------------
// FUSED memory-bound dispatch (256-thread, tiny-LDS blocks):
//   blocks 0..1023    : f2b of W_in (0..511) and W_out (512..1023)
//   blocks 1024..5119 : softmax+rel rows (one wave per (h,s) row)
// x is NOT converted here: gemm_xw consumes it f32 directly (saves 24MB).
// ---------------------------------------------------------------------------
__global__ __launch_bounds__(256) void k_sm_f2bw(
    const float* __restrict__ S, const float* __restrict__ relv,
    ushort_t* __restrict__ P, float* __restrict__ R,
    const float* __restrict__ Wi, const float* __restrict__ Wo,
    ushort_t* __restrict__ Wib, ushort_t* __restrict__ Wob)
{
  __shared__ float mid[4][16];

  if (blockIdx.x < 1024) {
    const float* in; ushort_t* out; int i;
    if (blockIdx.x < 512) { in = Wi; out = Wib; i = (blockIdx.x * 256 + threadIdx.x) * 8; }
    else                  { in = Wo; out = Wob; i = ((blockIdx.x - 512) * 256 + threadIdx.x) * 8; }
    float4 a = *reinterpret_cast<const float4*>(in + i);
    float4 b = *reinterpret_cast<const float4*>(in + i + 4);
    short8 o;
    o[0] = (short)f2b(a.x); o[1] = (short)f2b(a.y);
    o[2] = (short)f2b(a.z); o[3] = (short)f2b(a.w);
    o[4] = (short)f2b(b.x); o[5] = (short)f2b(b.y);
    o[6] = (short)f2b(b.z); o[7] = (short)f2b(b.w);
    *reinterpret_cast<short8*>(out + i) = o;
    return;
  }

  // ---- softmax + rel buckets (verified rounds 2-10) ----
  const int wave = threadIdx.x >> 6, lane = threadIdx.x & 63;
  const int row = (blockIdx.x - 1024) * 4 + wave;   // h*1024 + s
  const int s = row & 1023;
  const float* src = S + (size_t)row * 1024;

  float v[4][4];
#pragma unroll
  for (int c = 0; c < 4; ++c) {
    float4 raw = *reinterpret_cast<const float4*>(src + c * 256 + lane * 4);
    v[c][0] = raw.x; v[c][1] = raw.y; v[c][2] = raw.z; v[c][3] = raw.w;
  }
  float m = -1e30f;
#pragma unroll
  for (int c = 0; c < 4; ++c)
#pragma unroll
    for (int e = 0; e < 4; ++e) m = fmaxf(m, v[c][e]);
#pragma unroll
  for (int d = 32; d; d >>= 1) m = fmaxf(m, __shfl_xor(m, d));

  float p[4][4];
  float tot = 0.f, sA = 0.f, sB = 0.f;
#pragma unroll
  for (int c = 0; c < 4; ++c) {
#pragma unroll
    for (int e = 0; e < 4; ++e) {
      int j = c * 256 + lane * 4 + e;
      float pe = __expf(v[c][e] - m);
      p[c][e] = pe;
      tot += pe;
      sA += (j <= s - 8) ? pe : 0.f;
      sB += (j >= s + 8) ? pe : 0.f;
    }
  }
#pragma unroll
  for (int d = 32; d; d >>= 1) {
    tot += __shfl_xor(tot, d);
    sA  += __shfl_xor(sA, d);
    sB  += __shfl_xor(sB, d);
  }
  const float inv = 1.0f / tot;

  if (lane < 16) mid[wave][lane] = 0.f;
  __syncthreads();
#pragma unroll
  for (int c = 0; c < 4; ++c) {
#pragma unroll
    for (int e = 0; e < 4; ++e) {
      int j = c * 256 + lane * 4 + e;
      int tt = j - (s - 7);
      if (tt >= 0 && tt < 15) mid[wave][tt] = p[c][e];
    }
  }
  __syncthreads();

  float acc = sA * relv[lane] + sB * relv[16 * 64 + lane];
#pragma unroll
  for (int tt = 0; tt < 15; ++tt)
    acc += mid[wave][tt] * relv[(1 + tt) * 64 + lane];
  R[(size_t)row * 64 + lane] = acc * inv;

#pragma unroll
  for (int c = 0; c < 4; ++c) {
    short4_t o;
#pragma unroll
    for (int e = 0; e < 4; ++e) o[e] = (short)f2b(p[c][e] * inv);
    *reinterpret_cast<short4_t*>(P + (size_t)row * 1024 + c * 256 + lane * 4) = o;
  }
}

// ---------------------------------------------------------------------------
// Shared staging/compute macros (XOR swizzle source+read pair, rule 21).
// ---------------------------------------------------------------------------
#define STG(kt, buf)                                                        \
  {                                                                         \
    const int k0 = (kt) << 6;                                               \
    _Pragma("unroll")                                                       \
    for (int cc = 0; cc < 2; ++cc) {                                        \
      int c = threadIdx.x + (cc << 9);                                      \
      int r = c >> 3, cb = c & 7;                                           \
      int sc = k0 + ((cb ^ (r & 7)) << 3);                                  \
      gload16(A0 + (size_t)r * 1024 + sc, (char*)sA + (buf) * 16384 + c * 16); \
      gload16(B0 + (size_t)r * 1024 + sc, (char*)sB + (buf) * 16384 + c * 16); \
    }                                                                       \
  }

#define KSTEP_COMPUTE(bA, bB)                                               \
  _Pragma("unroll")                                                         \
  for (int kk = 0; kk < 2; ++kk) {                                          \
    const int cs = (kk << 2) + lk;                                          \
    short8 af[4], bf[2];                                                    \
    _Pragma("unroll")                                                       \
    for (int i = 0; i < 4; ++i) {                                           \
      int ra = (wm << 6) + (i << 4) + l15;                                  \
      af[i] = *reinterpret_cast<const short8*>(                             \
          (bA) + ra * 128 + ((cs ^ (ra & 7)) << 4));                        \
    }                                                                       \
    _Pragma("unroll")                                                       \
    for (int j = 0; j < 2; ++j) {                                           \
      int rb = (wn << 5) + (j << 4) + l15;                                  \
      bf[j] = *reinterpret_cast<const short8*>(                             \
          (bB) + rb * 128 + ((cs ^ (rb & 7)) << 4));                        \
    }                                                                       \
    __builtin_amdgcn_s_setprio(1);                                          \
    _Pragma("unroll")                                                       \
    for (int i = 0; i < 4; ++i)                                             \
      _Pragma("unroll")                                                     \
      for (int j = 0; j < 2; ++j)                                           \
        acc[i][j] = mfma16(af[i], bf[j], acc[i][j]);                        \
    __builtin_amdgcn_s_setprio(0);                                          \
  }

// ---------------------------------------------------------------------------
// 4-slot 128x128 GEMM core (VERIFIED round 7): depth-2 prefetch, counted
// vmcnt(8), one raw s_barrier per K-step. Slot reuse distance = 4 K-steps.
// ---------------------------------------------------------------------------
__device__ __forceinline__ void gemm128_loop4(
    const ushort_t* __restrict__ A0, const ushort_t* __restrict__ B0,
    ushort_t* sA, ushort_t* sB, floatx4 (&acc)[4][2])
{
  const int lane = threadIdx.x & 63, wave = threadIdx.x >> 6;
  const int wm = wave & 1, wn = wave >> 1;
  const int l15 = lane & 15, lk = lane >> 4;

  STG(0, 0);
  STG(1, 1);
  for (int kt = 0; kt < 16; ++kt) {
    if (kt < 14) {
      STG(kt + 2, (kt + 2) & 3);
      asm volatile("s_waitcnt vmcnt(8)" ::: "memory");
    } else if (kt == 14) {
      asm volatile("s_waitcnt vmcnt(4)" ::: "memory");
    } else {
      asm volatile("s_waitcnt vmcnt(0)" ::: "memory");
    }
    __builtin_amdgcn_s_barrier();
    const char* bA = (const char*)sA + (kt & 3) * 16384;
    const char* bB = (const char*)sB + (kt & 3) * 16384;
    KSTEP_COMPUTE(bA, bB);
  }
}

// bijective XCD swizzle for 256-block grids (256 % 8 == 0)
__device__ __forceinline__ int xcd_swz(int bid) {
  return ((bid & 7) << 5) | (bid >> 3);
}

// ---------------------------------------------------------------------------
// GEMM 1: Yt[h*256 + b*64 + d][s] = sum_k W_in[h*64+d][k] * x[b*1024+s][k]
// A = Wib (bf16, gload_lds), B = x (f32, reg-staged + cvt, T14 split).
// 2-phase __syncthreads loop (race-safe core verified round 9), 64KB LDS.
// ---------------------------------------------------------------------------
__global__ __launch_bounds__(512) void k_gemm_xw(
    const ushort_t* __restrict__ W, const float* __restrict__ Xf,
    ushort_t* __restrict__ Yt)
{
  __shared__ ushort_t sA[2 * 128 * 64];
  __shared__ ushort_t sB[2 * 128 * 64];
  const int lg = xcd_swz(blockIdx.x);
  const int m0 = (lg & 7) << 7, n0 = (lg >> 3) << 7;
  const ushort_t* A0 = W + (size_t)m0 * 1024;
  const float*    Bf = Xf + (size_t)n0 * 1024;

  const int lane = threadIdx.x & 63, wave = threadIdx.x >> 6;
  const int wm = wave & 1, wn = wave >> 1;
  const int l15 = lane & 15, lk = lane >> 4;
  floatx4 acc[4][2] = {};
  float4 breg[4];

#define STGA(kt, buf)                                                       \
  {                                                                         \
    const int k0 = (kt) << 6;                                               \
    _Pragma("unroll")                                                       \
    for (int cc = 0; cc < 2; ++cc) {                                        \
      int c = threadIdx.x + (cc << 9);                                      \
      int r = c >> 3, cb = c & 7;                                           \
      int sc = k0 + ((cb ^ (r & 7)) << 3);                                  \
      gload16(A0 + (size_t)r * 1024 + sc, (char*)sA + (buf) * 16384 + c * 16); \
    }                                                                       \
  }
#define LOADB(kt)                                                           \
  {                                                                         \
    const int k0 = (kt) << 6;                                               \
    _Pragma("unroll")                                                       \
    for (int cc = 0; cc < 2; ++cc) {                                        \
      int c = threadIdx.x + (cc << 9);                                      \
      int r = c >> 3, cb = c & 7;                                           \
      int sc = k0 + ((cb ^ (r & 7)) << 3);                                  \
      const float* srcp = Bf + (size_t)r * 1024 + sc;                       \
      breg[cc * 2]     = *reinterpret_cast<const float4*>(srcp);            \
      breg[cc * 2 + 1] = *reinterpret_cast<const float4*>(srcp + 4);        \
    }                                                                       \
  }
#define CVTW(buf)                                                           \
  {                                                                         \
    _Pragma("unroll")                                                       \
    for (int cc = 0; cc < 2; ++cc) {                                        \
      int c = threadIdx.x + (cc << 9);                                      \
      float4 va = breg[cc * 2], vb = breg[cc * 2 + 1];                      \
      short8 o;                                                             \
      o[0] = (short)cvtb(va.x); o[1] = (short)cvtb(va.y);                   \
      o[2] = (short)cvtb(va.z); o[3] = (short)cvtb(va.w);                   \
      o[4] = (short)cvtb(vb.x); o[5] = (short)cvtb(vb.y);                   \
      o[6] = (short)cvtb(vb.z); o[7] = (short)cvtb(vb.w);                   \
      *reinterpret_cast<short8*>((char*)sB + (buf) * 16384 + c * 16) = o;   \
    }                                                                       \
  }

  // prologue: tile 0 fully staged (compiler inserts the vmcnt for breg use)
  STGA(0, 0);
  LOADB(0);
  CVTW(0);
  for (int kt = 0; kt < 16; ++kt) {
    __syncthreads();   // drains: gloadA(kt) vmcnt, CVTW(kt) lgkm, prev reads
    if (kt < 15) { STGA(kt + 1, (kt + 1) & 1); LOADB(kt + 1); }
    const char* bA = (const char*)sA + (kt & 1) * 16384;
    const char* bB = (const char*)sB + (kt & 1) * 16384;
    KSTEP_COMPUTE(bA, bB);
    if (kt < 15) CVTW((kt + 1) & 1);   // after MFMAs: f32-load latency hidden
  }
#undef STGA
#undef LOADB
#undef CVTW

#pragma unroll
  for (int i = 0; i < 4; ++i)
#pragma unroll
    for (int j = 0; j < 2; ++j)
#pragma unroll
      for (int rr = 0; rr < 4; ++rr) {
        int wrow = m0 + (wm << 6) + (i << 4) + (lk << 2) + rr;  // h*64+d
        int col  = n0 + (wn << 5) + (j << 4) + l15;             // b*1024+s
        int h = wrow >> 6, d = wrow & 63;
        int b = col >> 10, s = col & 1023;
        Yt[(((size_t)((h << 2) + b) << 6) + d) * 1024 + s] = f2b(acc[i][j][rr]);
      }
}

// ---------------------------------------------------------------------------
// GEMM 2 (PV): O[b][s][h*64+d] = sum_j P[h][s][j]*Yt[h][b*64+d][j] + R[h][s][d]
// (verified round-7 core, unchanged)
// ---------------------------------------------------------------------------
__global__ __launch_bounds__(512) void k_head_pv(
    const ushort_t* __restrict__ P, const ushort_t* __restrict__ Yt,
    const float* __restrict__ R, ushort_t* __restrict__ O)
{
  __shared__ ushort_t sA[4 * 128 * 64];
  __shared__ ushort_t sB[4 * 128 * 64];
  const int lg = xcd_swz(blockIdx.x);
  const int h = lg >> 4, rem = lg & 15;
  const int m0 = (rem >> 1) << 7, n0 = (rem & 1) << 7;
  const ushort_t* A0 = P + ((size_t)h << 20) + (size_t)m0 * 1024;
  const ushort_t* B0 = Yt + ((size_t)h << 18) + (size_t)n0 * 1024;
  floatx4 acc[4][2] = {};
  gemm128_loop4(A0, B0, sA, sB, acc);

  const int lane = threadIdx.x & 63, wave = threadIdx.x >> 6;
  const int wm = wave & 1, wn = wave >> 1;
  const int l15 = lane & 15, lk = lane >> 4;
#pragma unroll
  for (int i = 0; i < 4; ++i)
#pragma unroll
    for (int j = 0; j < 2; ++j)
#pragma unroll
      for (int rr = 0; rr < 4; ++rr) {
        int sr = m0 + (wm << 6) + (i << 4) + (lk << 2) + rr;
        int c  = n0 + (wn << 5) + (j << 4) + l15;               // b*64+d
        int b = c >> 6, d = c & 63;
        float val = acc[i][j][rr] + R[(((size_t)h << 10) + sr) * 64 + d];
        O[((size_t)b << 20) + ((size_t)sr << 10) + (h << 6) + d] = f2b(val);
      }
}

// ---------------------------------------------------------------------------
// GEMM 3: out[m][n] = sum_k O[m][k] * W_out[n][k]  (f32 out).
// (verified round-7 core, unchanged)
// ---------------------------------------------------------------------------
__global__ __launch_bounds__(512) void k_gemm_out(
    const ushort_t* __restrict__ A, const ushort_t* __restrict__ B,
    float* __restrict__ C)
{
  __shared__ ushort_t sA[4 * 128 * 64];
  __shared__ ushort_t sB[4 * 128 * 64];
  const int lg = xcd_swz(blockIdx.x);
  const int m0 = (lg >> 3) << 7, n0 = (lg & 7) << 7;
  const ushort_t* A0 = A + (size_t)m0 * 1024;
  const ushort_t* B0 = B + (size_t)n0 * 1024;
  floatx4 acc[4][2] = {};
  gemm128_loop4(A0, B0, sA, sB, acc);

  const int lane = threadIdx.x & 63, wave = threadIdx.x >> 6;
  const int wm = wave & 1, wn = wave >> 1;
  const int l15 = lane & 15, lk = lane >> 4;
#pragma unroll
  for (int i = 0; i < 4; ++i)
#pragma unroll
    for (int j = 0; j < 2; ++j)
#pragma unroll
      for (int rr = 0; rr < 4; ++rr) {
        int rowg = m0 + (wm << 6) + (i << 4) + (lk << 2) + rr;
        int colg = n0 + (wn << 5) + (j << 4) + l15;
        C[(size_t)rowg * 1024 + colg] = acc[i][j][rr];
      }
}

// ---------------------------------------------------------------------------
extern "C" void kernel_launch(void* const* d_in, const int* in_sizes, int n_in,
                              void* d_out, int out_size, void* d_ws, size_t ws_size,
                              hipStream_t stream)
{
  const float* x     = (const float*)d_in[0];
  const float* W_in  = (const float*)d_in[1];
  const float* W_out = (const float*)d_in[2];
  const float* attn  = (const float*)d_in[3];
  const float* relv  = (const float*)d_in[4];
  float* out = (float*)d_out;

  char* ws = (char*)d_ws;
  ushort_t* Wib = (ushort_t*)(ws + (8u << 20));   //  2 MB
  ushort_t* Wob = (ushort_t*)(ws + (10u << 20));  //  2 MB
  ushort_t* P   = (ushort_t*)(ws + (12u << 20));  // 32 MB
  float*    R   = (float*)   (ws + (44u << 20));  //  4 MB
  ushort_t* Yt  = (ushort_t*)(ws + (48u << 20));  //  8 MB  [h*256+b*64+d][s]
  ushort_t* O   = (ushort_t*)(ws + (56u << 20));  //  8 MB  [b][s][h*64+d]

  k_sm_f2bw<<<5120, 256, 0, stream>>>(attn, relv, P, R, W_in, W_out, Wib, Wob);
  k_gemm_xw<<<256, 512, 0, stream>>>(Wib, x, Yt);
  k_head_pv<<<256, 512, 0, stream>>>(P, Yt, R, O);
  k_gemm_out<<<256, 512, 0, stream>>>(O, Wob, out);
}